// Round 4
// baseline (276.852 us; speedup 1.0000x reference)
//
#include <hip/hip_runtime.h>
#include <hip/hip_bf16.h>
#include <cstdint>

// Problem: B=256, N0=64, D0=128, N1=64, D1=128 (all fp32 in/out).
// u[b,n1,n0,d1] = sum_d0 x[b,n0,d0]*W[n1,n0,d0,d1]
// s = sum_n0 u ; logit = (u . s)/sqrt(128) ; c = softmax_n1(logit) + bias
// out[b,n1,d1] = sum_n0 u*c
//
// ws layout: u bf16 [B][N1][N0][D1]      @ 0          (268435456 B)
//            logits f32 [B][N1][N0]      @ 268435456  (4194304 B)
//            cc/xbf shared region        @ 272629760  (4194304 B)

#define BB 256
#define NN0 64
#define DD0 128
#define NN1 64
#define DD1 128

typedef __attribute__((ext_vector_type(8))) short bf16x8;
typedef __attribute__((ext_vector_type(4))) float f32x4;

__device__ __forceinline__ ushort f2bf(float f) {
  uint32_t b = __float_as_uint(f);
  b += 0x7FFFu + ((b >> 16) & 1u);      // RNE
  return (ushort)(b >> 16);
}
__device__ __forceinline__ float bf2f(ushort h) {
  return __uint_as_float(((uint32_t)h) << 16);
}

__device__ __forceinline__ void gld_lds16(const void* g, void* l) {
  __builtin_amdgcn_global_load_lds(
      (const __attribute__((address_space(1))) void*)g,
      (__attribute__((address_space(3))) void*)l, 16, 0, 0);
}

// ---------------- Px: x fp32 -> bf16
__global__ __launch_bounds__(512) void px_cvt(
    const float* __restrict__ x, ushort* __restrict__ xbf)
{
  int i = blockIdx.x * 512 + threadIdx.x;   // 524288 float4 chunks total
  float4 v = *reinterpret_cast<const float4*>(x + (size_t)i * 4);
  ushort4 h;
  h.x = f2bf(v.x); h.y = f2bf(v.y); h.z = f2bf(v.z); h.w = f2bf(v.w);
  *reinterpret_cast<ushort4*>(xbf + (size_t)i * 4) = h;
}

// ---------------- K1: block = (n0, group of 8 n1). A (x slice, M=256 x K=128)
// staged ONCE via global_load_lds; W streamed through double-buffered B-LDS,
// one barrier per K-step; per-n1 epilogue overlapped with next n1's W loads.
// LDS: A 64K | B0 16K | B1 16K | Epi 32K = 128 KB -> 1 block/CU, 512 blocks = 2 rounds.
__global__ __launch_bounds__(512, 2) void k1_gemm(
    const ushort* __restrict__ xbf, const float* __restrict__ W,
    ushort* __restrict__ u)
{
  __shared__ __align__(16) char lds[131072];
  char* Alds = lds;                         // 256 rows(b) x 256B (k=128 bf16), XOR-swz
  char* Bl0 = lds + 65536;                  // 128 rows(d1) x 128B (k=64 bf16), XOR-swz
  char* Bl1 = lds + 81920;
  char* Epi = lds + 98304;                  // 128 rows x 256B

  const int bid0 = blockIdx.x;
  const int b2 = (bid0 & 7) * 64 + (bid0 >> 3);   // XCD-contig (512 = 8*64): blocks on
  const int n0 = b2 >> 3, g = b2 & 7;             // one XCD share n0 -> x L2 reuse
  const int n1base = g * 8;
  const int t = threadIdx.x;
  const int lane = t & 63, wave = t >> 6;
  const int wm = wave >> 1, wn = wave & 1;        // 4 M-waves x 2 N-waves

  const ushort* xb = xbf + n0 * DD0;              // + b*8192 + d0
  ushort* ubase = u + (size_t)n0 * 128;           // + b*524288 + n1*8192 + d1

  f32x4 acc[4][4];
#pragma unroll
  for (int a = 0; a < 4; ++a)
#pragma unroll
    for (int b = 0; b < 4; ++b) acc[a][b] = {0.f, 0.f, 0.f, 0.f};

  // B gather constants (coalesced over d1; transposing scatter, proven 0-conflict)
  const int c0 = t, c1 = t + 512;
  const int bn0 = c0 & 127, bkc0 = c0 >> 7;       // d1 row, k-chunk (8 k's = 16 B)
  const int bn1 = c1 & 127, bkc1 = c1 >> 7;

  float hh[16];
  auto loadW = [&](const float* Wb, int h) {
#pragma unroll
    for (int j = 0; j < 8; ++j) hh[j]     = Wb[(size_t)(h * 64 + bkc0 * 8 + j) * 128 + bn0];
#pragma unroll
    for (int j = 0; j < 8; ++j) hh[8 + j] = Wb[(size_t)(h * 64 + bkc1 * 8 + j) * 128 + bn1];
  };
  auto packB = [&](char* Bb) {
    uint32_t p[8];
#pragma unroll
    for (int q = 0; q < 8; ++q)
      p[q] = (uint32_t)f2bf(hh[q * 2]) | ((uint32_t)f2bf(hh[q * 2 + 1]) << 16);
    *reinterpret_cast<uint4*>(Bb + ((bn0 * 128 + bkc0 * 16) ^ ((bn0 & 7) << 4))) =
        make_uint4(p[0], p[1], p[2], p[3]);
    *reinterpret_cast<uint4*>(Bb + ((bn1 * 128 + bkc1 * 16) ^ ((bn1 & 7) << 4))) =
        make_uint4(p[4], p[5], p[6], p[7]);
  };
  auto mfma_step = [&](int h, const char* Bb) {
#pragma unroll
    for (int kk = 0; kk < 64; kk += 32) {
      const int kb = kk + (lane >> 4) * 8;        // k within half
      const int ka = h * 64 + kb;                 // k within full 128
      bf16x8 af[4], bfr[4];
#pragma unroll
      for (int mf = 0; mf < 4; ++mf) {
        int row = wm * 64 + mf * 16 + (lane & 15);
        int byte = (row * 256 + ka * 2) ^ ((row & 7) << 4);
        af[mf] = *reinterpret_cast<const bf16x8*>(Alds + byte);
      }
#pragma unroll
      for (int nf = 0; nf < 4; ++nf) {
        int n = wn * 64 + nf * 16 + (lane & 15);
        int byte = (n * 128 + kb * 2) ^ ((n & 7) << 4);
        bfr[nf] = *reinterpret_cast<const bf16x8*>(Bb + byte);
      }
#pragma unroll
      for (int mf = 0; mf < 4; ++mf)
#pragma unroll
        for (int nf = 0; nf < 4; ++nf)
          acc[mf][nf] = __builtin_amdgcn_mfma_f32_16x16x32_bf16(af[mf], bfr[nf], acc[mf][nf], 0, 0, 0);
    }
  };

  // ---- prologue: stage A once (full K), issue first W loads
#pragma unroll
  for (int s = 0; s < 8; ++s) {
    int seg = wave * 8 + s;                       // 64 segs x 1024 B (4 rows)
    int row = seg * 4 + (lane >> 4);
    int srcc = (lane & 15) ^ (row & 7);           // source pre-swizzle
    gld_lds16(xb + (size_t)row * 8192 + srcc * 8, Alds + seg * 1024);
  }
  loadW(W + ((size_t)n1base * 64 + n0) * 16384, 0);

#pragma unroll 1
  for (int i = 0; i < 8; ++i) {
    const int n1 = n1base + i;
    const float* Wb = W + ((size_t)n1 * 64 + n0) * 16384;
    // K-half 0
    packB(Bl0);                     // consumes hh (loaded >=1 MFMA-phase ago)
    __syncthreads();                // drains A-DMA on first iter; B0 visible
    loadW(Wb, 1);                   // prefetch half-1, covered by MFMA below
    mfma_step(0, Bl0);
    // K-half 1
    packB(Bl1);
    __syncthreads();
    mfma_step(1, Bl1);

    // epilogue: 2 halves of 128 b-rows through Epi (32 KB), vector global writes
    ushort* ub = ubase + (size_t)n1 * 8192;
#pragma unroll
    for (int half = 0; half < 2; ++half) {
      __syncthreads();              // prev copy-out reads done; MFMA done
      if ((wm >> 1) == half) {
        int wml = wm & 1;
#pragma unroll
        for (int mf = 0; mf < 4; ++mf) {
          int rowb = wml * 64 + mf * 16 + (lane >> 4) * 4;
#pragma unroll
          for (int nf = 0; nf < 4; ++nf) {
            int col = wn * 64 + nf * 16 + (lane & 15);
#pragma unroll
            for (int r = 0; r < 4; ++r) {
              int rr = rowb + r;
              int byte = (rr * 256 + col * 2) ^ ((rr & 7) << 4);
              *reinterpret_cast<ushort*>(Epi + byte) = f2bf(acc[mf][nf][r]);
            }
          }
        }
      }
      __syncthreads();
      if (half == 1 && i < 7)       // prefetch next n1 half-0; consumed by next
        loadW(W + ((size_t)(n1 + 1) * 64 + n0) * 16384, 0);  // pack BEFORE next barrier
#pragma unroll
      for (int ci = 0; ci < 4; ++ci) {
        int c = t + ci * 512;       // 2048 x 16B chunks
        int rowl = c >> 4;
        int cb = (c & 15) * 16;
        int sbyte = (rowl * 256 + cb) ^ ((rowl & 7) << 4);
        uint4 v = *reinterpret_cast<uint4*>(Epi + sbyte);
        int row = half * 128 + rowl;
        *reinterpret_cast<uint4*>(ub + (size_t)row * 524288 + cb / 2) = v;
      }
    }
#pragma unroll
    for (int a = 0; a < 4; ++a)
#pragma unroll
      for (int b = 0; b < 4; ++b) acc[a][b] = {0.f, 0.f, 0.f, 0.f};
  }
}

// ---------------- K2: s = sum_n0 u ; logits = (u . s)/sqrt(128)
__global__ __launch_bounds__(256) void k2_logits(
    const ushort* __restrict__ u, float* __restrict__ logits)
{
  const int bid = blockIdx.x;           // b*64 + n1
  const ushort* up = u + (size_t)bid * 8192;   // [n0][d1] 64x128
  const int t = threadIdx.x;

  __shared__ float part[8][128];
  __shared__ float sS[128];
  __shared__ float part2[256];

  {
    int d4 = (t & 31) * 4;
    int g = t >> 5;                     // n0 group of 8
    float4 a = {0, 0, 0, 0};
    for (int n0 = g * 8; n0 < g * 8 + 8; ++n0) {
      ushort4 v = *reinterpret_cast<const ushort4*>(up + n0 * 128 + d4);
      a.x += bf2f(v.x); a.y += bf2f(v.y); a.z += bf2f(v.z); a.w += bf2f(v.w);
    }
    *reinterpret_cast<float4*>(&part[g][d4]) = a;
  }
  __syncthreads();
  if (t < 128) {
    float s = 0;
#pragma unroll
    for (int g = 0; g < 8; ++g) s += part[g][t];
    sS[t] = s;
  }
  __syncthreads();
  {
    int n0 = t >> 2, q = t & 3;
    float acc = 0;
#pragma unroll
    for (int j = 0; j < 32; j += 4) {
      int d = q * 32 + j;
      ushort4 v = *reinterpret_cast<const ushort4*>(up + n0 * 128 + d);
      acc += bf2f(v.x) * sS[d] + bf2f(v.y) * sS[d + 1] + bf2f(v.z) * sS[d + 2] + bf2f(v.w) * sS[d + 3];
    }
    part2[t] = acc;
  }
  __syncthreads();
  if (t < 64) {
    float l = (part2[t * 4] + part2[t * 4 + 1] + part2[t * 4 + 2] + part2[t * 4 + 3]) * 0.08838834764831845f;
    logits[(size_t)bid * 64 + t] = l;
  }
}

// ---------------- K3: softmax over n1 (per (b,n0)) + bias
__global__ __launch_bounds__(64) void k3_softmax(
    const float* __restrict__ logits, const float* __restrict__ bias,
    float* __restrict__ cc)
{
  const int b = blockIdx.x;
  const int t = threadIdx.x;            // = n0
  __shared__ float L[64][64];           // [n1][n0]
  const float* lp = logits + (size_t)b * 4096;
  for (int i = 0; i < 64; ++i) L[i][t] = lp[i * 64 + t];
  __syncthreads();
  float m = -1e30f;
#pragma unroll
  for (int n1 = 0; n1 < 64; ++n1) m = fmaxf(m, L[n1][t]);
  float sum = 0.f;
#pragma unroll
  for (int n1 = 0; n1 < 64; ++n1) {
    float e = __expf(L[n1][t] - m);
    L[n1][t] = e;
    sum += e;
  }
  float inv = 1.0f / sum;
  float* cp = cc + (size_t)b * 4096;
  for (int n1 = 0; n1 < 64; ++n1)
    cp[n1 * 64 + t] = L[n1][t] * inv + bias[n1 * 64 + t];
}

// ---------------- K4: out[b,n1,d1] = sum_n0 u * c
__global__ __launch_bounds__(128) void k4_out(
    const ushort* __restrict__ u, const float* __restrict__ cc,
    float* __restrict__ out)
{
  const int bid = blockIdx.x;           // b*64 + n1
  const ushort* up = u + (size_t)bid * 8192;
  const int t = threadIdx.x;
  __shared__ float cL[64];
  __shared__ float part[4][128];
  if (t < 64) cL[t] = cc[(size_t)bid * 64 + t];
  __syncthreads();
  int d4 = (t & 31) * 4, g = t >> 5;    // g: n0 group of 16
  float4 a = {0, 0, 0, 0};
  for (int n0 = g * 16; n0 < g * 16 + 16; ++n0) {
    ushort4 v = *reinterpret_cast<const ushort4*>(up + n0 * 128 + d4);
    float c = cL[n0];
    a.x += bf2f(v.x) * c; a.y += bf2f(v.y) * c; a.z += bf2f(v.z) * c; a.w += bf2f(v.w) * c;
  }
  *reinterpret_cast<float4*>(&part[g][d4]) = a;
  __syncthreads();
  if (t < 128) {
    float r = part[0][t] + part[1][t] + part[2][t] + part[3][t];
    out[(size_t)bid * 128 + t] = r;
  }
}

extern "C" void kernel_launch(void* const* d_in, const int* in_sizes, int n_in,
                              void* d_out, int out_size, void* d_ws, size_t ws_size,
                              hipStream_t stream) {
  const float* x = (const float*)d_in[0];
  const float* W = (const float*)d_in[1];
  const float* bias = (const float*)d_in[2];
  float* out = (float*)d_out;

  ushort* u = (ushort*)d_ws;                                   // 268435456 B
  float* logits = (float*)((char*)d_ws + 268435456u);          // 4194304 B
  char* ccxbf = (char*)d_ws + 272629760u;                      // 4194304 B shared
  ushort* xbf = (ushort*)ccxbf;     // live Px..K1
  float* cc = (float*)ccxbf;        // live K3..K4 (overwrites xbf after K1 done)

  hipLaunchKernelGGL(px_cvt,     dim3(1024),     dim3(512), 0, stream, x, xbf);
  hipLaunchKernelGGL(k1_gemm,    dim3(512),      dim3(512), 0, stream, xbf, W, u);
  hipLaunchKernelGGL(k2_logits,  dim3(BB * NN1), dim3(256), 0, stream, u, logits);
  hipLaunchKernelGGL(k3_softmax, dim3(BB),       dim3(64),  0, stream, logits, bias, cc);
  hipLaunchKernelGGL(k4_out,     dim3(BB * NN1), dim3(128), 0, stream, u, cc, out);
}